// Round 1
// baseline (4665.884 us; speedup 1.0000x reference)
//
#include <hip/hip_runtime.h>

#define GRID    256
#define BLOCK   512
#define NWAVES  (BLOCK / 64)
#define CHUNK   7813   // ceil(2e6/256); 3*CHUNK*4 = 93756 B dynamic LDS (160 KB/CU)
#define KMAX    8      // speculative substeps per communication round

typedef unsigned long long u64;

// ---------------- fence-free tagged publish (cross-XCD safe) ----------------
// r14 = speculative K-step batching. History: grid.sync 28.5us (r2); acquire
// polls 33us (r3); release-fence 12.7us (r4); fence-free tagged 9.7us (r5);
// SoA all-to-all 8.4us (r6, verified-bad); leader + 64-lane broadcast 6.05us
// (r8); Ii hoist (r13, 5.77us/step). r14 exploits: per-step chain is latency-
// bound (VALUBusy 13.6%), and the no-contact update is closed-form, so every
// block replicates an 8-step ballistic walk bit-exactly and tests each vertex
// against all 8 planes per round. Leader verifies num_k==0 per step (exact:
// f32 counts < 2^24); on contact it computes the impulse at step k, truncates
// the round, and K drops to 1 until a clean round (worst case == r13 perf).
// Tags: round+1 (<=241) and 0xC0FFEE; harness poison 0xAAAAAAAA matches
// neither. Graph-replay safe: all published words are deterministic functions
// of the inputs, so stale words from a prior replay are bitwise identical.
__device__ __forceinline__ u64 rec_load(const u64* p) {
  return __hip_atomic_load(p, __ATOMIC_RELAXED, __HIP_MEMORY_SCOPE_AGENT);
}
__device__ __forceinline__ void rec_store(u64* p, u64 v) {
  __hip_atomic_store(p, v, __ATOMIC_RELAXED, __HIP_MEMORY_SCOPE_AGENT);
}
__device__ __forceinline__ u64 rec_pack(float f, unsigned tag) {
  return (u64)__float_as_uint(f) | ((u64)tag << 32);
}

// ---------------- block reduction: NV values, result in thread 0 ----------------
template <int NV>
__device__ __forceinline__ void block_reduce(float* v, float* sm) {
  #pragma unroll
  for (int off = 32; off > 0; off >>= 1) {
    #pragma unroll
    for (int k = 0; k < NV; ++k) v[k] += __shfl_down(v[k], off, 64);
  }
  const int lane = threadIdx.x & 63;
  const int wid  = threadIdx.x >> 6;
  if (lane == 0) {
    #pragma unroll
    for (int k = 0; k < NV; ++k) sm[wid * NV + k] = v[k];
  }
  __syncthreads();
  if (threadIdx.x == 0) {
    #pragma unroll
    for (int w = 1; w < NWAVES; ++w) {
      #pragma unroll
      for (int k = 0; k < NV; ++k) v[k] += sm[w * NV + k];
    }
  }
  __syncthreads();
}

// ---------------- 3x3 helpers (row-major float[9]) ----------------
__device__ __forceinline__ void mat3_mul(const float* A, const float* B, float* C) {
  #pragma unroll
  for (int i = 0; i < 3; ++i)
    #pragma unroll
    for (int j = 0; j < 3; ++j)
      C[i*3+j] = A[i*3+0]*B[0*3+j] + A[i*3+1]*B[1*3+j] + A[i*3+2]*B[2*3+j];
}
__device__ __forceinline__ void mat3_mul_bt(const float* A, const float* B, float* C) {
  #pragma unroll
  for (int i = 0; i < 3; ++i)
    #pragma unroll
    for (int j = 0; j < 3; ++j)
      C[i*3+j] = A[i*3+0]*B[j*3+0] + A[i*3+1]*B[j*3+1] + A[i*3+2]*B[j*3+2];
}
__device__ __forceinline__ void mat3_inv(const float* m, float* inv) {
  float A =  (m[4]*m[8] - m[5]*m[7]);
  float B = -(m[3]*m[8] - m[5]*m[6]);
  float C =  (m[3]*m[7] - m[4]*m[6]);
  float det = m[0]*A + m[1]*B + m[2]*C;
  float id = 1.0f / det;
  inv[0] = A * id;
  inv[1] = -(m[1]*m[8] - m[2]*m[7]) * id;
  inv[2] =  (m[1]*m[5] - m[2]*m[4]) * id;
  inv[3] = B * id;
  inv[4] =  (m[0]*m[8] - m[2]*m[6]) * id;
  inv[5] = -(m[0]*m[5] - m[2]*m[3]) * id;
  inv[6] = C * id;
  inv[7] = -(m[0]*m[7] - m[1]*m[6]) * id;
  inv[8] =  (m[0]*m[4] - m[1]*m[3]) * id;
}

__global__ __launch_bounds__(BLOCK)
void sim_kernel(const float* __restrict__ xg,
                const float* __restrict__ mc_p,
                const float* __restrict__ itr_p,
                const float* __restrict__ iq_p,
                const float* __restrict__ iv_p,
                const float* __restrict__ kn_p,
                const float* __restrict__ mu_p,
                const float* __restrict__ ldp_p,
                const float* __restrict__ adp_p,
                float* __restrict__ out,
                u64* __restrict__ ws,
                int N, int T)
{
  const int tid = threadIdx.x;
  const int bid = blockIdx.x;

  extern __shared__ float dyn[];
  float* sXx = dyn;
  float* sXy = dyn + CHUNK;
  float* sXz = dyn + 2 * CHUNK;
  __shared__ float s_red[NWAVES * 4 * KMAX];   // 256 floats
  __shared__ float s_planes[KMAX][8];          // per-step plane params
  __shared__ float s_traj[KMAX + 1][13];       // speculated states S_0..S_Kr
  __shared__ float s_tot[4 * KMAX];            // leader: reduced totals
  __shared__ float s_state[16];                // verdict: state(13)+meta+pad
  __shared__ int   s_mode;                     // 1 = omega==0 fast path

  // fp32 constants exactly as the fp32 reference sees them
  const float nx  = (float)(-0.3420201433256687);   // -sin(20deg)
  const float ny  = (float)( 0.9396926207859084);   //  cos(20deg)
  const float DTF = (float)(1.0 / 60.0 / 10.0);
  const float HDT = (float)(0.5 * (1.0 / 60.0 / 10.0));
  const float DTH = (float)(-0.9396926207859084 * 0.1); // -COS_S*INIT_HEIGHT
  const float GYDT = -9.8f * (float)(1.0 / 60.0 / 10.0);

  const float mc0 = mc_p[0], mc1 = mc_p[1], mc2 = mc_p[2];

  // workspace layout (u64):
  //   part: 2 bufs * GRID blocks * 32 words (AoS per block: w = 4k+c)
  //   st:   2 bufs * 4 replicas * 16 words (verdict)
  //   bufI: 6*GRID inertia partials
  u64* part = ws;                          // 16384
  u64* st   = ws + 2 * GRID * 32;          // 128
  u64* bufI = ws + 2 * GRID * 32 + 128;    // 1536   => 144,384 B total

  const int vstart = bid * CHUNK;
  int cl = N - vstart; if (cl > CHUNK) cl = CHUNK; if (cl < 0) cl = 0;

  // ---- stage this block's slice of x into LDS (SoA), single global pass ----
  for (int i = tid; i < cl; i += BLOCK) {
    const float* p = xg + (size_t)(vstart + i) * 3;
    sXx[i] = p[0]; sXy[i] = p[1]; sXz[i] = p[2];
  }
  __syncthreads();

  // ---- inertia partial: S[i][j] = sum r_i r_j over this slice ----
  {
    float v6[6] = {0,0,0,0,0,0};
    for (int i = tid; i < cl; i += BLOCK) {
      float r0 = sXx[i] - mc0, r1 = sXy[i] - mc1, r2 = sXz[i] - mc2;
      v6[0] += r0*r0; v6[1] += r1*r1; v6[2] += r2*r2;
      v6[3] += r0*r1; v6[4] += r0*r2; v6[5] += r1*r2;
    }
    block_reduce<6>(v6, s_red);
    if (tid == 0) {
      #pragma unroll
      for (int k = 0; k < 6; ++k) rec_store(bufI + k * GRID + bid, rec_pack(v6[k], 0xC0FFEEu));
    }
  }

  // ---- ONLY the leader gathers inertia (contact physics runs only there) ----
  float In[9];
  if (bid == 0) {
    float v6[6] = {0,0,0,0,0,0};
    if (tid < GRID) {
      u64 r[6];
      int f = 0;
      for (;;) {
        #pragma unroll
        for (int k = 0; k < 6; ++k) r[k] = rec_load(bufI + k * GRID + tid);
        bool ok = true;
        #pragma unroll
        for (int k = 0; k < 6; ++k) ok &= ((unsigned)(r[k] >> 32) == 0xC0FFEEu);
        if (ok) break;
        if ((++f & 15) == 0) __builtin_amdgcn_s_sleep(1);
      }
      #pragma unroll
      for (int k = 0; k < 6; ++k) v6[k] = __uint_as_float((unsigned)r[k]);
    }
    block_reduce<6>(v6, s_red);
    float trc = v6[0] + v6[1] + v6[2];
    In[0] = trc - v6[0]; In[4] = trc - v6[1]; In[8] = trc - v6[2];
    In[1] = -v6[3]; In[3] = -v6[3];
    In[2] = -v6[4]; In[6] = -v6[4];
    In[5] = -v6[5]; In[7] = -v6[5];
  }

  // ---- initial state; EVERY block's thread 0 holds an identical copy ----
  float tr0 = itr_p[0], tr1 = itr_p[1], tr2 = itr_p[2];
  float q0 = iq_p[0], q1 = iq_p[1], q2 = iq_p[2], q3 = iq_p[3];
  {
    float n0 = sqrtf(q0*q0 + q1*q1 + q2*q2 + q3*q3);
    q0 /= n0; q1 /= n0; q2 /= n0; q3 /= n0;
  }
  float v0 = iv_p[0], v1 = iv_p[1], v2 = iv_p[2];
  float om0 = 0.f, om1 = 0.f, om2 = 0.f;
  const float knv = kn_p[0], muv = mu_p[0], ldv = ldp_p[0], adv = adp_p[0];
  const float inv_mass = 1.0f / (float)N;

  int t_base = 0;
  int rnd = 0;
  int Ksched = KMAX;

  while (t_base < T) {
    const int rem = T - t_base;
    const int Kr = (Ksched < rem) ? Ksched : rem;
    const unsigned want = (unsigned)(rnd + 1);

    // ==== thread 0: speculative ballistic walk -> planes + trajectory ====
    if (tid == 0) {
      int mode1 = (om0 == 0.f && om1 == 0.f && om2 == 0.f) ? 1 : 0;
      s_mode = mode1;
      #pragma unroll
      for (int k = 0; k < KMAX; ++k) {
        if (k < Kr) {
          s_traj[k][0] = tr0; s_traj[k][1] = tr1; s_traj[k][2] = tr2;
          s_traj[k][3] = q0;  s_traj[k][4] = q1;  s_traj[k][5] = q2;  s_traj[k][6] = q3;
          s_traj[k][7] = v0;  s_traj[k][8] = v1;  s_traj[k][9] = v2;
          s_traj[k][10] = om0; s_traj[k][11] = om1; s_traj[k][12] = om2;
          float qn = sqrtf(q0*q0 + q1*q1 + q2*q2 + q3*q3);
          float w = q0/qn, xq = q1/qn, yq = q2/qn, zq = q3/qn;
          float R0 = 1.f - 2.f*yq*yq - 2.f*zq*zq, R1 = 2.f*xq*yq - 2.f*w*zq, R2 = 2.f*xq*zq + 2.f*w*yq;
          float R3 = 2.f*xq*yq + 2.f*w*zq, R4 = 1.f - 2.f*xq*xq - 2.f*zq*zq, R5 = 2.f*yq*zq - 2.f*w*xq;
          float R6 = 2.f*xq*zq - 2.f*w*yq, R7 = 2.f*yq*zq + 2.f*w*xq, R8 = 1.f - 2.f*xq*xq - 2.f*yq*yq;
          float a0 = R0*nx + R3*ny;
          float a1 = R1*nx + R4*ny;
          float a2 = R2*nx + R5*ny;
          float w0 = ny*om2, w1 = -nx*om2, w2 = nx*om1 - ny*om0;
          float b0 = R0*w0 + R3*w1 + R6*w2;
          float b1 = R1*w0 + R4*w1 + R7*w2;
          float b2 = R2*w0 + R5*w1 + R8*w2;
          float ca = DTH - ((tr0 + mc0)*nx + (tr1 + mc1)*ny);
          float cb = -(v0*nx + v1*ny);
          if (mode1) {
            // omega==0 -> db = +-0 exactly; step active iff cb > 0
            if (cb > 0.f) {
              s_planes[k][0] = a0; s_planes[k][1] = a1; s_planes[k][2] = a2; s_planes[k][3] = ca;
            } else {
              s_planes[k][0] = 0.f; s_planes[k][1] = 0.f; s_planes[k][2] = 0.f; s_planes[k][3] = -1e30f;
            }
          } else {
            s_planes[k][0] = a0; s_planes[k][1] = a1; s_planes[k][2] = a2; s_planes[k][3] = ca;
            s_planes[k][4] = b0; s_planes[k][5] = b1; s_planes[k][6] = b2; s_planes[k][7] = cb;
          }
          // ballistic advance (dv = 0, domega = 0)
          v0 = v0*ldv; v1 = (v1 + GYDT)*ldv; v2 = v2*ldv;
          om0 = om0*adv; om1 = om1*adv; om2 = om2*adv;
          tr0 += DTF*v0; tr1 += DTF*v1; tr2 += DTF*v2;
          float wx = om0*HDT, wy = om1*HDT, wz = om2*HDT;
          float dq0 = -wx*q1 - wy*q2 - wz*q3;
          float dq1 =  wx*q0 + wy*q3 - wz*q2;
          float dq2 =  wy*q0 + wz*q1 - wx*q3;
          float dq3 =  wz*q0 + wx*q2 - wy*q1;
          q0 += dq0; q1 += dq1; q2 += dq2; q3 += dq3;
          float qn2 = sqrtf(q0*q0 + q1*q1 + q2*q2 + q3*q3);
          q0 /= qn2; q1 /= qn2; q2 /= qn2; q3 /= qn2;
        } else {
          // sentinel: never matches
          s_planes[k][0] = 0.f; s_planes[k][1] = 0.f; s_planes[k][2] = 0.f; s_planes[k][3] = -1e30f;
          s_planes[k][4] = 0.f; s_planes[k][5] = 0.f; s_planes[k][6] = 0.f; s_planes[k][7] = -1e30f;
        }
      }
      s_traj[Kr][0] = tr0; s_traj[Kr][1] = tr1; s_traj[Kr][2] = tr2;
      s_traj[Kr][3] = q0;  s_traj[Kr][4] = q1;  s_traj[Kr][5] = q2;  s_traj[Kr][6] = q3;
      s_traj[Kr][7] = v0;  s_traj[Kr][8] = v1;  s_traj[Kr][9] = v2;
      s_traj[Kr][10] = om0; s_traj[Kr][11] = om1; s_traj[Kr][12] = om2;
    }
    __syncthreads();

    // ==== masked reduction: each vertex tested against all KMAX planes ====
    float accf[4 * KMAX];
    #pragma unroll
    for (int w = 0; w < 4 * KMAX; ++w) accf[w] = 0.f;

    if (s_mode) {
      float pa0[KMAX], pa1[KMAX], pa2[KMAX], pca[KMAX];
      #pragma unroll
      for (int k = 0; k < KMAX; ++k) {
        pa0[k] = s_planes[k][0]; pa1[k] = s_planes[k][1];
        pa2[k] = s_planes[k][2]; pca[k] = s_planes[k][3];
      }
      for (int i = tid; i < cl; i += BLOCK) {
        float x0 = sXx[i], x1 = sXy[i], x2 = sXz[i];
        #pragma unroll
        for (int k = 0; k < KMAX; ++k) {
          float da = x0*pa0[k] + x1*pa1[k] + x2*pa2[k];
          float sel = (da < pca[k]) ? 1.f : 0.f;
          accf[k*4+0] += sel;
          accf[k*4+1] = fmaf(sel, x0, accf[k*4+1]);
          accf[k*4+2] = fmaf(sel, x1, accf[k*4+2]);
          accf[k*4+3] = fmaf(sel, x2, accf[k*4+3]);
        }
      }
    } else {
      float pa0[KMAX], pa1[KMAX], pa2[KMAX], pca[KMAX];
      float pb0[KMAX], pb1[KMAX], pb2[KMAX], pcb[KMAX];
      #pragma unroll
      for (int k = 0; k < KMAX; ++k) {
        pa0[k] = s_planes[k][0]; pa1[k] = s_planes[k][1];
        pa2[k] = s_planes[k][2]; pca[k] = s_planes[k][3];
        pb0[k] = s_planes[k][4]; pb1[k] = s_planes[k][5];
        pb2[k] = s_planes[k][6]; pcb[k] = s_planes[k][7];
      }
      for (int i = tid; i < cl; i += BLOCK) {
        float x0 = sXx[i], x1 = sXy[i], x2 = sXz[i];
        #pragma unroll
        for (int k = 0; k < KMAX; ++k) {
          float da = x0*pa0[k] + x1*pa1[k] + x2*pa2[k];
          float db = x0*pb0[k] + x1*pb1[k] + x2*pb2[k];
          float sel = (da < pca[k] && db < pcb[k]) ? 1.f : 0.f;
          accf[k*4+0] += sel;
          accf[k*4+1] = fmaf(sel, x0, accf[k*4+1]);
          accf[k*4+2] = fmaf(sel, x1, accf[k*4+2]);
          accf[k*4+3] = fmaf(sel, x2, accf[k*4+3]);
        }
      }
    }

    // ==== block reduce (wave shfl tree + cross-wave), publish by 32 lanes ====
    #pragma unroll
    for (int off = 32; off > 0; off >>= 1) {
      #pragma unroll
      for (int w = 0; w < 4 * KMAX; ++w) accf[w] += __shfl_down(accf[w], off, 64);
    }
    {
      const int lane = tid & 63, wid = tid >> 6;
      if (lane == 0) {
        #pragma unroll
        for (int w = 0; w < 4 * KMAX; ++w) s_red[wid * 32 + w] = accf[w];
      }
    }
    __syncthreads();
    {
      u64* pb = part + (size_t)(rnd & 1) * GRID * 32 + (size_t)bid * 32;
      if (tid < 32) {
        float tw = s_red[tid];
        #pragma unroll
        for (int ww = 1; ww < NWAVES; ++ww) tw += s_red[ww * 32 + tid];
        rec_store(pb + tid, rec_pack(tw, want));
      }
    }

    if (bid == 0) {
      __syncthreads();   // protect s_red: publish-readers vs gather-writers

      // ---- gather: 512 lanes, lane = (block, half), 16 words each ----
      float tot[4 * KMAX];
      #pragma unroll
      for (int w = 0; w < 4 * KMAX; ++w) tot[w] = 0.f;
      {
        const u64* pp = part + (size_t)(rnd & 1) * GRID * 32
                             + (size_t)(tid >> 1) * 32 + (size_t)(tid & 1) * 16;
        u64 r[16];
        int f = 0;
        for (;;) {
          #pragma unroll
          for (int w = 0; w < 16; ++w) r[w] = rec_load(pp + w);
          bool ok = true;
          #pragma unroll
          for (int w = 0; w < 16; ++w) ok &= ((unsigned)(r[w] >> 32) == want);
          if (ok) break;
          if ((++f & 15) == 0) __builtin_amdgcn_s_sleep(1);
        }
        if ((tid & 1) == 0) {
          #pragma unroll
          for (int w = 0; w < 16; ++w) tot[w] = __uint_as_float((unsigned)r[w]);
        } else {
          #pragma unroll
          for (int w = 0; w < 16; ++w) tot[16 + w] = __uint_as_float((unsigned)r[w]);
        }
      }
      #pragma unroll
      for (int off = 32; off > 0; off >>= 1) {
        #pragma unroll
        for (int w = 0; w < 4 * KMAX; ++w) tot[w] += __shfl_down(tot[w], off, 64);
      }
      {
        const int lane = tid & 63, wid = tid >> 6;
        if (lane == 0) {
          #pragma unroll
          for (int w = 0; w < 4 * KMAX; ++w) s_red[wid * 32 + w] = tot[w];
        }
      }
      __syncthreads();
      if (tid < 32) {
        float tw = s_red[tid];
        #pragma unroll
        for (int ww = 1; ww < NWAVES; ++ww) tw += s_red[ww * 32 + tid];
        s_tot[tid] = tw;
      }
      __syncthreads();

      // ---- verdict walk (thread 0): verify speculation step by step ----
      if (tid == 0) {
        int consumed = Kr;
        unsigned contact = 0;
        float f0=0,f1=0,f2=0,f3=0,f4=0,f5=0,f6=0,f7=0,f8=0,f9=0,f10=0,f11=0,f12=0;
        #pragma unroll
        for (int k = 0; k < KMAX; ++k) {
          if (k < Kr && !contact) {
            float num = s_tot[4*k+0];
            if (num > 0.0f) {
              // contact at step t_base+k: full impulse physics from stored state
              float btr0=s_traj[k][0], btr1=s_traj[k][1], btr2=s_traj[k][2];
              float bq0=s_traj[k][3], bq1=s_traj[k][4], bq2=s_traj[k][5], bq3=s_traj[k][6];
              float bv0=s_traj[k][7], bv1=s_traj[k][8], bv2=s_traj[k][9];
              float bo0=s_traj[k][10], bo1=s_traj[k][11], bo2=s_traj[k][12];
              float qn = sqrtf(bq0*bq0 + bq1*bq1 + bq2*bq2 + bq3*bq3);
              float w = bq0/qn, xq = bq1/qn, yq = bq2/qn, zq = bq3/qn;
              float Rm[9];
              Rm[0] = 1.f - 2.f*yq*yq - 2.f*zq*zq; Rm[1] = 2.f*xq*yq - 2.f*w*zq; Rm[2] = 2.f*xq*zq + 2.f*w*yq;
              Rm[3] = 2.f*xq*yq + 2.f*w*zq; Rm[4] = 1.f - 2.f*xq*xq - 2.f*zq*zq; Rm[5] = 2.f*yq*zq - 2.f*w*xq;
              Rm[6] = 2.f*xq*zq - 2.f*w*yq; Rm[7] = 2.f*yq*zq + 2.f*w*xq; Rm[8] = 1.f - 2.f*xq*xq - 2.f*yq*yq;
              float Tm[9]; mat3_mul(Rm, In, Tm);
              float Iw[9]; mat3_mul_bt(Tm, Rm, Iw);
              float Ii[9]; mat3_inv(Iw, Ii);
              float numf = fmaxf(num, 1.0f);
              float ri0 = s_tot[4*k+1]/numf, ri1 = s_tot[4*k+2]/numf, ri2 = s_tot[4*k+3]/numf;
              float Ri0 = Rm[0]*ri0 + Rm[1]*ri1 + Rm[2]*ri2;
              float Ri1 = Rm[3]*ri0 + Rm[4]*ri1 + Rm[5]*ri2;
              float Ri2 = Rm[6]*ri0 + Rm[7]*ri1 + Rm[8]*ri2;
              float vi0 = bv0 + bo1*Ri2 - bo2*Ri1;
              float vi1 = bv1 + bo2*Ri0 - bo0*Ri2;
              float vi2 = bv2 + bo0*Ri1 - bo1*Ri0;
              float vdn = vi0*nx + vi1*ny;
              float vn0 = vdn*nx, vn1 = vdn*ny;            // vn2 == 0 exactly
              float vt0 = vi0 - vn0, vt1 = vi1 - vn1, vt2 = vi2;
              float nvn = sqrtf(vn0*vn0 + vn1*vn1);
              float nvt = sqrtf(vt0*vt0 + vt1*vt1 + vt2*vt2);
              float alpha = fmaxf(1.0f - muv*(1.0f + knv)*(nvn/(nvt + 1e-6f)), 0.0f);
              float dvi0 = (-knv*vn0 + alpha*vt0) - vi0;
              float dvi1 = (-knv*vn1 + alpha*vt1) - vi1;
              float dvi2 = (alpha*vt2) - vi2;
              float Cx[9] = {0.f, -Ri2, Ri1,  Ri2, 0.f, -Ri0,  -Ri1, Ri0, 0.f};
              float T2[9]; mat3_mul(Cx, Ii, T2);
              float T3[9]; mat3_mul(T2, Cx, T3);
              float Km[9];
              #pragma unroll
              for (int m = 0; m < 9; ++m) Km[m] = -T3[m];
              Km[0] += inv_mass; Km[4] += inv_mass; Km[8] += inv_mass;
              float Ki[9]; mat3_inv(Km, Ki);
              float J0 = Ki[0]*dvi0 + Ki[1]*dvi1 + Ki[2]*dvi2;
              float J1 = Ki[3]*dvi0 + Ki[4]*dvi1 + Ki[5]*dvi2;
              float J2 = Ki[6]*dvi0 + Ki[7]*dvi1 + Ki[8]*dvi2;
              float dv0 = J0*inv_mass, dv1 = J1*inv_mass, dv2 = J2*inv_mass;
              float c0 = -Ri2*J1 + Ri1*J2;
              float c1 =  Ri2*J0 - Ri0*J2;
              float c2 = -Ri1*J0 + Ri0*J1;
              float dm0 = Ii[0]*c0 + Ii[1]*c1 + Ii[2]*c2;
              float dm1 = Ii[3]*c0 + Ii[4]*c1 + Ii[5]*c2;
              float dm2 = Ii[6]*c0 + Ii[7]*c1 + Ii[8]*c2;
              bv0 = bv0*ldv + dv0;
              bv1 = (bv1 + GYDT)*ldv + dv1;
              bv2 = bv2*ldv + dv2;
              bo0 = bo0*adv + dm0; bo1 = bo1*adv + dm1; bo2 = bo2*adv + dm2;
              btr0 += DTF*bv0; btr1 += DTF*bv1; btr2 += DTF*bv2;
              float wx = bo0*HDT, wy = bo1*HDT, wz = bo2*HDT;
              float dq0 = -wx*bq1 - wy*bq2 - wz*bq3;
              float dq1 =  wx*bq0 + wy*bq3 - wz*bq2;
              float dq2 =  wy*bq0 + wz*bq1 - wx*bq3;
              float dq3 =  wz*bq0 + wx*bq2 - wy*bq1;
              bq0 += dq0; bq1 += dq1; bq2 += dq2; bq3 += dq3;
              float qn2 = sqrtf(bq0*bq0 + bq1*bq1 + bq2*bq2 + bq3*bq3);
              bq0 /= qn2; bq1 /= qn2; bq2 /= qn2; bq3 /= qn2;
              float* o = out + (size_t)(t_base + k) * 7;
              o[0] = btr0; o[1] = btr1; o[2] = btr2;
              o[3] = bq0;  o[4] = bq1;  o[5] = bq2;  o[6] = bq3;
              f0=btr0; f1=btr1; f2=btr2; f3=bq0; f4=bq1; f5=bq2; f6=bq3;
              f7=bv0; f8=bv1; f9=bv2; f10=bo0; f11=bo1; f12=bo2;
              consumed = k + 1; contact = 1;
            } else {
              // clean step: speculated ballistic state is authoritative
              float* o = out + (size_t)(t_base + k) * 7;
              #pragma unroll
              for (int j = 0; j < 7; ++j) o[j] = s_traj[k+1][j];
            }
          }
        }
        if (!contact) {
          f0=s_traj[Kr][0]; f1=s_traj[Kr][1]; f2=s_traj[Kr][2];
          f3=s_traj[Kr][3]; f4=s_traj[Kr][4]; f5=s_traj[Kr][5]; f6=s_traj[Kr][6];
          f7=s_traj[Kr][7]; f8=s_traj[Kr][8]; f9=s_traj[Kr][9];
          f10=s_traj[Kr][10]; f11=s_traj[Kr][11]; f12=s_traj[Kr][12];
        }
        s_state[0]=f0; s_state[1]=f1; s_state[2]=f2;
        s_state[3]=f3; s_state[4]=f4; s_state[5]=f5; s_state[6]=f6;
        s_state[7]=f7; s_state[8]=f8; s_state[9]=f9;
        s_state[10]=f10; s_state[11]=f11; s_state[12]=f12;
        s_state[13] = __uint_as_float((unsigned)consumed | (contact << 8));
        s_state[14] = 0.f; s_state[15] = 0.f;
      }
      __syncthreads();
      // ---- broadcast: 4 replicas x 16 words, one coalesced 64-lane store ----
      if (tid < 64) {
        u64* sl = st + (size_t)(rnd & 1) * 64;
        rec_store(sl + tid, rec_pack(s_state[tid & 15], want));
      }
    } else {
      // ---- non-leader: poll my replica of the verdict line ----
      if (tid < 16) {
        const u64* sl = st + (size_t)(rnd & 1) * 64 + (size_t)(bid & 3) * 16;
        u64 r; int f = 0;
        for (;;) {
          r = rec_load(sl + tid);
          if ((unsigned)(r >> 32) == want) break;
          if ((++f & 31) == 0) __builtin_amdgcn_s_sleep(1);
        }
        s_state[tid] = __uint_as_float((unsigned)r);
      }
      __syncthreads();
    }

    // ==== all blocks: adopt verdict (uniform) ====
    {
      unsigned meta = __float_as_uint(s_state[13]);
      int consumed = (int)(meta & 0xFFu);
      int contact  = (int)((meta >> 8) & 1u);
      if (tid == 0) {
        tr0 = s_state[0]; tr1 = s_state[1]; tr2 = s_state[2];
        q0 = s_state[3]; q1 = s_state[4]; q2 = s_state[5]; q3 = s_state[6];
        v0 = s_state[7]; v1 = s_state[8]; v2 = s_state[9];
        om0 = s_state[10]; om1 = s_state[11]; om2 = s_state[12];
      }
      t_base += consumed;
      Ksched = contact ? 1 : KMAX;
      ++rnd;
    }
  }
}

extern "C" void kernel_launch(void* const* d_in, const int* in_sizes, int n_in,
                              void* d_out, int out_size, void* d_ws, size_t ws_size,
                              hipStream_t stream) {
  const float* x   = (const float*)d_in[0];
  const float* mc  = (const float*)d_in[1];
  const float* itr = (const float*)d_in[2];
  const float* iq  = (const float*)d_in[3];
  const float* iv  = (const float*)d_in[4];
  const float* kn  = (const float*)d_in[5];
  const float* mu  = (const float*)d_in[6];
  const float* ldp = (const float*)d_in[7];
  const float* adp = (const float*)d_in[8];
  float* out = (float*)d_out;
  u64* ws  = (u64*)d_ws;
  int N = in_sizes[0] / 3;
  int T = out_size / 7;

  const int dyn_lds = 3 * CHUNK * 4;   // 93756 B < 160 KB/CU
  hipFuncSetAttribute((const void*)sim_kernel,
                      hipFuncAttributeMaxDynamicSharedMemorySize, dyn_lds);

  void* args[] = {(void*)&x, (void*)&mc, (void*)&itr, (void*)&iq, (void*)&iv,
                  (void*)&kn, (void*)&mu, (void*)&ldp, (void*)&adp,
                  (void*)&out, (void*)&ws, (void*)&N, (void*)&T};
  // cooperative launch kept ONLY for the co-residency guarantee (no grid.sync inside)
  hipLaunchCooperativeKernel((void*)sim_kernel, dim3(GRID), dim3(BLOCK),
                             args, dyn_lds, stream);
}

// Round 2
// 1516.367 us; speedup vs baseline: 3.0770x; 3.0770x over previous
//
#include <hip/hip_runtime.h>

#define GRID    256
#define BLOCK   512
#define NWAVES  (BLOCK / 64)
#define CHUNK   7813   // ceil(2e6/256); 3*CHUNK*4 = 93756 B dynamic LDS (160 KB/CU)
#define KMAX    8
#define NREP    16     // verdict replicas (>= r13 poll-density per line)

typedef unsigned long long u64;

// ---------------- fence-free tagged publish (cross-XCD safe) ----------------
// r15 = adaptive K-batching with r13-lean payloads. r14 post-mortem:
// WRITE_SIZE 15.15MB == ~237 rounds x 256B AoS publish => contact (or
// truncation) nearly every step; Ksched pinned at 1, but every K=1 round
// still paid the 8-plane loop + 32-word payload + 4-replica verdict hotspot
// (~1024 pollers/line) => 19.6us/round. r15: per-K templates (K=1 ==
// r13 4-word shape), decentralized state (verdict = meta + state-on-contact
// only), pow2ceil(consumed) schedule that locks onto period-2 bounce
// alternation (one clean + one contact step per K=2 round), 16-replica
// verdict lines (~224 pollers/line), out-writes after broadcast, and
// zero-comms skip rounds while omega==0 && rel_v test uniform-inactive.
// Tags: round+1 and 0xC0FFEE; poison 0xAAAAAAAA matches neither. All
// published words deterministic => graph-replay safe (stale == identical).
__device__ __forceinline__ u64 rec_load(const u64* p) {
  return __hip_atomic_load(p, __ATOMIC_RELAXED, __HIP_MEMORY_SCOPE_AGENT);
}
__device__ __forceinline__ void rec_store(u64* p, u64 v) {
  __hip_atomic_store(p, v, __ATOMIC_RELAXED, __HIP_MEMORY_SCOPE_AGENT);
}
__device__ __forceinline__ u64 rec_pack(float f, unsigned tag) {
  return (u64)__float_as_uint(f) | ((u64)tag << 32);
}

// exact fp32 constants as the fp32 reference sees them
#define C_NX   ((float)(-0.3420201433256687))
#define C_NY   ((float)( 0.9396926207859084))
#define C_DTF  ((float)(1.0 / 60.0 / 10.0))
#define C_HDT  ((float)(0.5 * (1.0 / 60.0 / 10.0)))
#define C_DTH  ((float)(-0.9396926207859084 * 0.1))
#define C_GYDT (-9.8f * (float)(1.0 / 60.0 / 10.0))

// ---------------- block reduction: NV values, result in thread 0 ----------------
template <int NV>
__device__ __forceinline__ void block_reduce(float* v, float* sm) {
  #pragma unroll
  for (int off = 32; off > 0; off >>= 1) {
    #pragma unroll
    for (int k = 0; k < NV; ++k) v[k] += __shfl_down(v[k], off, 64);
  }
  const int lane = threadIdx.x & 63;
  const int wid  = threadIdx.x >> 6;
  if (lane == 0) {
    #pragma unroll
    for (int k = 0; k < NV; ++k) sm[wid * NV + k] = v[k];
  }
  __syncthreads();
  if (threadIdx.x == 0) {
    #pragma unroll
    for (int w = 1; w < NWAVES; ++w) {
      #pragma unroll
      for (int k = 0; k < NV; ++k) v[k] += sm[w * NV + k];
    }
  }
  __syncthreads();
}

// ---------------- 3x3 helpers (row-major float[9]) ----------------
__device__ __forceinline__ void mat3_mul(const float* A, const float* B, float* C) {
  #pragma unroll
  for (int i = 0; i < 3; ++i)
    #pragma unroll
    for (int j = 0; j < 3; ++j)
      C[i*3+j] = A[i*3+0]*B[0*3+j] + A[i*3+1]*B[1*3+j] + A[i*3+2]*B[2*3+j];
}
__device__ __forceinline__ void mat3_mul_bt(const float* A, const float* B, float* C) {
  #pragma unroll
  for (int i = 0; i < 3; ++i)
    #pragma unroll
    for (int j = 0; j < 3; ++j)
      C[i*3+j] = A[i*3+0]*B[j*3+0] + A[i*3+1]*B[j*3+1] + A[i*3+2]*B[j*3+2];
}
__device__ __forceinline__ void mat3_inv(const float* m, float* inv) {
  float A =  (m[4]*m[8] - m[5]*m[7]);
  float B = -(m[3]*m[8] - m[5]*m[6]);
  float C =  (m[3]*m[7] - m[4]*m[6]);
  float det = m[0]*A + m[1]*B + m[2]*C;
  float id = 1.0f / det;
  inv[0] = A * id;
  inv[1] = -(m[1]*m[8] - m[2]*m[7]) * id;
  inv[2] =  (m[1]*m[5] - m[2]*m[4]) * id;
  inv[3] = B * id;
  inv[4] =  (m[0]*m[8] - m[2]*m[6]) * id;
  inv[5] = -(m[0]*m[5] - m[2]*m[3]) * id;
  inv[6] = C * id;
  inv[7] = -(m[0]*m[7] - m[1]*m[6]) * id;
  inv[8] =  (m[0]*m[4] - m[1]*m[3]) * id;
}

// ---------------- one protocol round, K compile-time sized ----------------
template<int KT>
__device__ __forceinline__ void run_round(
    int Kr, unsigned want, int buf, int t_base,
    float& tr0, float& tr1, float& tr2,
    float& q0, float& q1, float& q2, float& q3,
    float& v0, float& v1, float& v2,
    float& om0, float& om1, float& om2,
    float knv, float muv, float ldv, float adv,
    float inv_mass, float mc0, float mc1,
    const float* In,
    const float* sXx, const float* sXy, const float* sXz, int cl,
    float* s_red, float (*s_planes)[8], float (*s_traj)[13],
    float* s_tot, float* s_state, int* s_flags,
    u64* part, u64* st, float* __restrict__ out,
    int& consumed, int& contact, int& skipped)
{
  constexpr int NW = (KT <= 4) ? 4 * KT : 12;
  const int tid = threadIdx.x;
  const int bid = blockIdx.x;

  // ==== tid0: speculative ballistic walk -> planes + trajectory ====
  if (tid == 0) {
    const int mode1 = (om0 == 0.f && om1 == 0.f && om2 == 0.f) ? 1 : 0;
    int allin = mode1;
    #pragma unroll
    for (int k = 0; k < KT; ++k) {
      if (k < Kr) {
        s_traj[k][0] = tr0; s_traj[k][1] = tr1; s_traj[k][2] = tr2;
        s_traj[k][3] = q0;  s_traj[k][4] = q1;  s_traj[k][5] = q2;  s_traj[k][6] = q3;
        s_traj[k][7] = v0;  s_traj[k][8] = v1;  s_traj[k][9] = v2;
        s_traj[k][10] = om0; s_traj[k][11] = om1; s_traj[k][12] = om2;
        float qn = sqrtf(q0*q0 + q1*q1 + q2*q2 + q3*q3);
        float w = q0/qn, xq = q1/qn, yq = q2/qn, zq = q3/qn;
        float R0 = 1.f - 2.f*yq*yq - 2.f*zq*zq, R1 = 2.f*xq*yq - 2.f*w*zq, R2 = 2.f*xq*zq + 2.f*w*yq;
        float R3 = 2.f*xq*yq + 2.f*w*zq, R4 = 1.f - 2.f*xq*xq - 2.f*zq*zq, R5 = 2.f*yq*zq - 2.f*w*xq;
        float R6 = 2.f*xq*zq - 2.f*w*yq, R7 = 2.f*yq*zq + 2.f*w*xq, R8 = 1.f - 2.f*xq*xq - 2.f*yq*yq;
        float a0 = R0*C_NX + R3*C_NY;
        float a1 = R1*C_NX + R4*C_NY;
        float a2 = R2*C_NX + R5*C_NY;
        float w0 = C_NY*om2, w1 = -C_NX*om2, w2 = C_NX*om1 - C_NY*om0;
        float b0 = R0*w0 + R3*w1 + R6*w2;
        float b1 = R1*w0 + R4*w1 + R7*w2;
        float b2 = R2*w0 + R5*w1 + R8*w2;
        float ca = C_DTH - ((tr0 + mc0)*C_NX + (tr1 + mc1)*C_NY);
        float cb = -(v0*C_NX + v1*C_NY);
        if (mode1) {
          // omega==0 -> db = +-0 exactly for all verts; step active iff cb > 0
          s_planes[k][0] = a0; s_planes[k][1] = a1; s_planes[k][2] = a2;
          s_planes[k][3] = (cb > 0.f) ? ca : -1e30f;
          if (cb > 0.f) allin = 0;
        } else {
          s_planes[k][0] = a0; s_planes[k][1] = a1; s_planes[k][2] = a2; s_planes[k][3] = ca;
          s_planes[k][4] = b0; s_planes[k][5] = b1; s_planes[k][6] = b2; s_planes[k][7] = cb;
          allin = 0;
        }
        // ballistic advance (dv = 0, domega = 0) — bitwise == reference num==0 path
        v0 = v0*ldv; v1 = (v1 + C_GYDT)*ldv; v2 = v2*ldv;
        om0 = om0*adv; om1 = om1*adv; om2 = om2*adv;
        tr0 += C_DTF*v0; tr1 += C_DTF*v1; tr2 += C_DTF*v2;
        float wx = om0*C_HDT, wy = om1*C_HDT, wz = om2*C_HDT;
        float dq0 = -wx*q1 - wy*q2 - wz*q3;
        float dq1 =  wx*q0 + wy*q3 - wz*q2;
        float dq2 =  wy*q0 + wz*q1 - wx*q3;
        float dq3 =  wz*q0 + wx*q2 - wy*q1;
        q0 += dq0; q1 += dq1; q2 += dq2; q3 += dq3;
        float qn2 = sqrtf(q0*q0 + q1*q1 + q2*q2 + q3*q3);
        q0 /= qn2; q1 /= qn2; q2 /= qn2; q3 /= qn2;
      } else {
        // sentinels never match (stale a/b stay finite)
        s_planes[k][3] = -1e30f;
        s_planes[k][7] = -1e30f;
      }
    }
    s_traj[Kr][0] = tr0; s_traj[Kr][1] = tr1; s_traj[Kr][2] = tr2;
    s_traj[Kr][3] = q0;  s_traj[Kr][4] = q1;  s_traj[Kr][5] = q2;  s_traj[Kr][6] = q3;
    s_traj[Kr][7] = v0;  s_traj[Kr][8] = v1;  s_traj[Kr][9] = v2;
    s_traj[Kr][10] = om0; s_traj[Kr][11] = om1; s_traj[Kr][12] = om2;
    *s_flags = mode1 | (allin << 1);
  }
  __syncthreads();
  const int flags = *s_flags;
  const int mode1 = flags & 1;

  if (flags & 2) {
    // all planes provably inactive (uniform, deterministic on every block):
    // clean round with ZERO protocol traffic.
    consumed = Kr; contact = 0; skipped = 1;
    if (bid == 0 && tid == 0) {
      for (int k = 0; k < Kr; ++k) {
        float* o = out + (size_t)(t_base + k) * 7;
        #pragma unroll
        for (int j = 0; j < 7; ++j) o[j] = s_traj[k+1][j];
      }
    }
    return;   // tid0 state regs already = S_Kr
  }
  skipped = 0;

  // ==== vertex pass(es) + publish ====
  if constexpr (KT <= 4) {
    // fused per-k (num,sx,sy,sz); KT==1 degenerates to the r13 loop exactly
    float acc[4 * KT];
    #pragma unroll
    for (int w = 0; w < 4 * KT; ++w) acc[w] = 0.f;
    if (mode1) {
      const float a0 = s_planes[0][0], a1 = s_planes[0][1], a2 = s_planes[0][2];
      float pca[KT];
      #pragma unroll
      for (int k = 0; k < KT; ++k) pca[k] = s_planes[k][3];
      for (int i = tid; i < cl; i += BLOCK) {
        const float x0 = sXx[i], x1 = sXy[i], x2 = sXz[i];
        const float da = x0*a0 + x1*a1 + x2*a2;   // a identical across k (omega==0)
        #pragma unroll
        for (int k = 0; k < KT; ++k) {
          const float sel = (da < pca[k]) ? 1.f : 0.f;
          acc[4*k+0] += sel;
          acc[4*k+1] = fmaf(sel, x0, acc[4*k+1]);
          acc[4*k+2] = fmaf(sel, x1, acc[4*k+2]);
          acc[4*k+3] = fmaf(sel, x2, acc[4*k+3]);
        }
      }
    } else {
      float pa0[KT], pa1[KT], pa2[KT], pca[KT];
      float pb0[KT], pb1[KT], pb2[KT], pcb[KT];
      #pragma unroll
      for (int k = 0; k < KT; ++k) {
        pa0[k] = s_planes[k][0]; pa1[k] = s_planes[k][1];
        pa2[k] = s_planes[k][2]; pca[k] = s_planes[k][3];
        pb0[k] = s_planes[k][4]; pb1[k] = s_planes[k][5];
        pb2[k] = s_planes[k][6]; pcb[k] = s_planes[k][7];
      }
      for (int i = tid; i < cl; i += BLOCK) {
        const float x0 = sXx[i], x1 = sXy[i], x2 = sXz[i];
        #pragma unroll
        for (int k = 0; k < KT; ++k) {
          const float da = x0*pa0[k] + x1*pa1[k] + x2*pa2[k];
          const float db = x0*pb0[k] + x1*pb1[k] + x2*pb2[k];
          const float sel = (da < pca[k] && db < pcb[k]) ? 1.f : 0.f;
          acc[4*k+0] += sel;
          acc[4*k+1] = fmaf(sel, x0, acc[4*k+1]);
          acc[4*k+2] = fmaf(sel, x1, acc[4*k+2]);
          acc[4*k+3] = fmaf(sel, x2, acc[4*k+3]);
        }
      }
    }
    #pragma unroll
    for (int off = 32; off > 0; off >>= 1)
      #pragma unroll
      for (int w = 0; w < 4 * KT; ++w) acc[w] += __shfl_down(acc[w], off, 64);
    {
      const int lane = tid & 63, wid = tid >> 6;
      if (lane == 0) {
        #pragma unroll
        for (int w = 0; w < 4 * KT; ++w) s_red[wid * (4*KT) + w] = acc[w];
      }
    }
    __syncthreads();
    if (tid < 4 * KT) {
      float tw = s_red[tid];
      #pragma unroll
      for (int ww = 1; ww < NWAVES; ++ww) tw += s_red[ww * (4*KT) + tid];
      rec_store(part + (size_t)buf * 16 * GRID + (size_t)tid * GRID + bid,
                rec_pack(tw, want));
    }
  } else {
    // KT == 8: pass1 counts, pass2 sums for this block's first-contact k
    float cnt[8];
    #pragma unroll
    for (int k = 0; k < 8; ++k) cnt[k] = 0.f;
    if (mode1) {
      const float a0 = s_planes[0][0], a1 = s_planes[0][1], a2 = s_planes[0][2];
      float pca[8];
      #pragma unroll
      for (int k = 0; k < 8; ++k) pca[k] = s_planes[k][3];
      for (int i = tid; i < cl; i += BLOCK) {
        const float x0 = sXx[i], x1 = sXy[i], x2 = sXz[i];
        const float da = x0*a0 + x1*a1 + x2*a2;
        #pragma unroll
        for (int k = 0; k < 8; ++k) cnt[k] += (da < pca[k]) ? 1.f : 0.f;
      }
    } else {
      float pa0[8], pa1[8], pa2[8], pca[8], pb0[8], pb1[8], pb2[8], pcb[8];
      #pragma unroll
      for (int k = 0; k < 8; ++k) {
        pa0[k] = s_planes[k][0]; pa1[k] = s_planes[k][1];
        pa2[k] = s_planes[k][2]; pca[k] = s_planes[k][3];
        pb0[k] = s_planes[k][4]; pb1[k] = s_planes[k][5];
        pb2[k] = s_planes[k][6]; pcb[k] = s_planes[k][7];
      }
      for (int i = tid; i < cl; i += BLOCK) {
        const float x0 = sXx[i], x1 = sXy[i], x2 = sXz[i];
        #pragma unroll
        for (int k = 0; k < 8; ++k) {
          const float da = x0*pa0[k] + x1*pa1[k] + x2*pa2[k];
          const float db = x0*pb0[k] + x1*pb1[k] + x2*pb2[k];
          cnt[k] += (da < pca[k] && db < pcb[k]) ? 1.f : 0.f;
        }
      }
    }
    #pragma unroll
    for (int off = 32; off > 0; off >>= 1)
      #pragma unroll
      for (int k = 0; k < 8; ++k) cnt[k] += __shfl_down(cnt[k], off, 64);
    {
      const int lane = tid & 63, wid = tid >> 6;
      if (lane == 0) {
        #pragma unroll
        for (int k = 0; k < 8; ++k) s_red[wid * 8 + k] = cnt[k];
      }
    }
    __syncthreads();
    if (tid < 8) {
      float tw = s_red[tid];
      #pragma unroll
      for (int ww = 1; ww < NWAVES; ++ww) tw += s_red[ww * 8 + tid];
      s_tot[tid] = tw;
    }
    __syncthreads();
    int kmin = KMAX;
    for (int k = Kr - 1; k >= 0; --k) if (s_tot[k] > 0.f) kmin = k;
    float sm[4] = {0.f, 0.f, 0.f, 0.f};
    if (kmin < Kr) {
      const float a0 = s_planes[kmin][0], a1 = s_planes[kmin][1], a2 = s_planes[kmin][2];
      const float ca = s_planes[kmin][3];
      if (mode1) {
        for (int i = tid; i < cl; i += BLOCK) {
          const float x0 = sXx[i], x1 = sXy[i], x2 = sXz[i];
          const float da = x0*a0 + x1*a1 + x2*a2;
          const float sel = (da < ca) ? 1.f : 0.f;
          sm[0] += sel;
          sm[1] = fmaf(sel, x0, sm[1]);
          sm[2] = fmaf(sel, x1, sm[2]);
          sm[3] = fmaf(sel, x2, sm[3]);
        }
      } else {
        const float b0 = s_planes[kmin][4], b1 = s_planes[kmin][5], b2 = s_planes[kmin][6];
        const float cb = s_planes[kmin][7];
        for (int i = tid; i < cl; i += BLOCK) {
          const float x0 = sXx[i], x1 = sXy[i], x2 = sXz[i];
          const float da = x0*a0 + x1*a1 + x2*a2;
          const float db = x0*b0 + x1*b1 + x2*b2;
          const float sel = (da < ca && db < cb) ? 1.f : 0.f;
          sm[0] += sel;
          sm[1] = fmaf(sel, x0, sm[1]);
          sm[2] = fmaf(sel, x1, sm[2]);
          sm[3] = fmaf(sel, x2, sm[3]);
        }
      }
    }
    #pragma unroll
    for (int off = 32; off > 0; off >>= 1)
      #pragma unroll
      for (int j = 0; j < 4; ++j) sm[j] += __shfl_down(sm[j], off, 64);
    {
      const int lane = tid & 63, wid = tid >> 6;
      if (lane == 0) {
        #pragma unroll
        for (int j = 0; j < 4; ++j) s_red[wid * 4 + j] = sm[j];
      }
    }
    __syncthreads();
    if (tid < 12) {
      float tw;
      if (tid < 8) tw = s_tot[tid];
      else {
        const int j = tid - 8;
        tw = s_red[j];
        #pragma unroll
        for (int ww = 1; ww < NWAVES; ++ww) tw += s_red[ww * 4 + j];
      }
      rec_store(part + (size_t)buf * 16 * GRID + (size_t)tid * GRID + bid,
                rec_pack(tw, want));
    }
  }

  // ==== leader: gather + verdict; others: poll verdict ====
  if (bid == 0) {
    __syncthreads();   // publish-finalize reads of s_red/s_tot done
    u64 r[NW];
    float f[NW];
    #pragma unroll
    for (int w = 0; w < NW; ++w) f[w] = 0.f;
    if (tid < GRID) {
      const u64* pp = part + (size_t)buf * 16 * GRID + tid;
      int fl = 0;
      for (;;) {
        #pragma unroll
        for (int w = 0; w < NW; ++w) r[w] = rec_load(pp + (size_t)w * GRID);
        bool ok = true;
        #pragma unroll
        for (int w = 0; w < NW; ++w) ok &= ((unsigned)(r[w] >> 32) == want);
        if (ok) break;
        if ((++fl & 15) == 0) __builtin_amdgcn_s_sleep(1);
      }
      #pragma unroll
      for (int w = 0; w < NW; ++w) f[w] = __uint_as_float((unsigned)r[w]);
    }
    float onum[8]; float os0 = 0.f, os1 = 0.f, os2 = 0.f;
    if constexpr (KT == 8) {
      #pragma unroll
      for (int k = 0; k < 8; ++k) onum[k] = f[k];
      os0 = f[9]; os1 = f[10]; os2 = f[11];
    } else {
      #pragma unroll
      for (int k = 0; k < 8; ++k) onum[k] = 0.f;
    }
    #pragma unroll
    for (int off = 32; off > 0; off >>= 1)
      #pragma unroll
      for (int w = 0; w < NW; ++w) f[w] += __shfl_down(f[w], off, 64);
    {
      const int lane = tid & 63, wid = tid >> 6;
      if (lane == 0) {
        #pragma unroll
        for (int w = 0; w < NW; ++w) s_red[wid * NW + w] = f[w];
      }
    }
    __syncthreads();
    if (tid < NW) {
      float tw = s_red[tid];
      #pragma unroll
      for (int ww = 1; ww < NWAVES; ++ww) tw += s_red[ww * NW + tid];
      s_tot[tid] = tw;
    }
    __syncthreads();
    int kg = -1;
    if constexpr (KT <= 4) {
      for (int k = Kr - 1; k >= 0; --k) if (s_tot[4*k] > 0.f) kg = k;
    } else {
      for (int k = Kr - 1; k >= 0; --k) if (s_tot[k] > 0.f) kg = k;
    }
    if constexpr (KT == 8) {
      if (kg >= 0) {
        // filtered sums: include block iff it had contact at kg (its kmin==kg)
        float myn = 0.f;
        #pragma unroll
        for (int k = 0; k < 8; ++k) myn = (k == kg) ? onum[k] : myn;
        const bool inc = (tid < GRID) && (myn > 0.f);
        float s3[3];
        s3[0] = inc ? os0 : 0.f; s3[1] = inc ? os1 : 0.f; s3[2] = inc ? os2 : 0.f;
        #pragma unroll
        for (int off = 32; off > 0; off >>= 1)
          #pragma unroll
          for (int j = 0; j < 3; ++j) s3[j] += __shfl_down(s3[j], off, 64);
        const int lane = tid & 63, wid = tid >> 6;
        if (lane == 0) {
          #pragma unroll
          for (int j = 0; j < 3; ++j) s_red[wid * 3 + j] = s3[j];
        }
        __syncthreads();
        if (tid < 3) {
          float tw = s_red[tid];
          #pragma unroll
          for (int ww = 1; ww < NWAVES; ++ww) tw += s_red[ww * 3 + tid];
          s_tot[13 + tid] = tw;
        }
        __syncthreads();
      }
    }

    // ---- verdict (tid0) ----
    if (tid == 0) {
      s_state[14] = 0.f; s_state[15] = 0.f;
      if (kg < 0) {
        s_state[13] = __uint_as_float((unsigned)Kr);   // clean: consumed=Kr, contact=0
      } else {
        float num, sx, sy, sz;
        if constexpr (KT <= 4) {
          num = s_tot[4*kg + 0]; sx = s_tot[4*kg + 1]; sy = s_tot[4*kg + 2]; sz = s_tot[4*kg + 3];
        } else {
          num = s_tot[kg]; sx = s_tot[13]; sy = s_tot[14]; sz = s_tot[15];
        }
        // contact physics at step t_base+kg from the stored pre-step state
        float btr0 = s_traj[kg][0], btr1 = s_traj[kg][1], btr2 = s_traj[kg][2];
        float bq0 = s_traj[kg][3], bq1 = s_traj[kg][4], bq2 = s_traj[kg][5], bq3 = s_traj[kg][6];
        float bv0 = s_traj[kg][7], bv1 = s_traj[kg][8], bv2 = s_traj[kg][9];
        float bo0 = s_traj[kg][10], bo1 = s_traj[kg][11], bo2 = s_traj[kg][12];
        float qn = sqrtf(bq0*bq0 + bq1*bq1 + bq2*bq2 + bq3*bq3);
        float w = bq0/qn, xq = bq1/qn, yq = bq2/qn, zq = bq3/qn;
        float Rm[9];
        Rm[0] = 1.f - 2.f*yq*yq - 2.f*zq*zq; Rm[1] = 2.f*xq*yq - 2.f*w*zq; Rm[2] = 2.f*xq*zq + 2.f*w*yq;
        Rm[3] = 2.f*xq*yq + 2.f*w*zq; Rm[4] = 1.f - 2.f*xq*xq - 2.f*zq*zq; Rm[5] = 2.f*yq*zq - 2.f*w*xq;
        Rm[6] = 2.f*xq*zq - 2.f*w*yq; Rm[7] = 2.f*yq*zq + 2.f*w*xq; Rm[8] = 1.f - 2.f*xq*xq - 2.f*yq*yq;
        float Tm[9]; mat3_mul(Rm, In, Tm);
        float Iw[9]; mat3_mul_bt(Tm, Rm, Iw);
        float Ii[9]; mat3_inv(Iw, Ii);
        float numf = fmaxf(num, 1.0f);
        float ri0 = sx/numf, ri1 = sy/numf, ri2 = sz/numf;
        float Ri0 = Rm[0]*ri0 + Rm[1]*ri1 + Rm[2]*ri2;
        float Ri1 = Rm[3]*ri0 + Rm[4]*ri1 + Rm[5]*ri2;
        float Ri2 = Rm[6]*ri0 + Rm[7]*ri1 + Rm[8]*ri2;
        float vi0 = bv0 + bo1*Ri2 - bo2*Ri1;
        float vi1 = bv1 + bo2*Ri0 - bo0*Ri2;
        float vi2 = bv2 + bo0*Ri1 - bo1*Ri0;
        float vdn = vi0*C_NX + vi1*C_NY;
        float vn0 = vdn*C_NX, vn1 = vdn*C_NY;            // vn2 == 0 exactly
        float vt0 = vi0 - vn0, vt1 = vi1 - vn1, vt2 = vi2;
        float nvn = sqrtf(vn0*vn0 + vn1*vn1);
        float nvt = sqrtf(vt0*vt0 + vt1*vt1 + vt2*vt2);
        float alpha = fmaxf(1.0f - muv*(1.0f + knv)*(nvn/(nvt + 1e-6f)), 0.0f);
        float dvi0 = (-knv*vn0 + alpha*vt0) - vi0;
        float dvi1 = (-knv*vn1 + alpha*vt1) - vi1;
        float dvi2 = (alpha*vt2) - vi2;
        float Cx[9] = {0.f, -Ri2, Ri1,  Ri2, 0.f, -Ri0,  -Ri1, Ri0, 0.f};
        float T2[9]; mat3_mul(Cx, Ii, T2);
        float T3[9]; mat3_mul(T2, Cx, T3);
        float Km[9];
        #pragma unroll
        for (int m = 0; m < 9; ++m) Km[m] = -T3[m];
        Km[0] += inv_mass; Km[4] += inv_mass; Km[8] += inv_mass;
        float Ki[9]; mat3_inv(Km, Ki);
        float J0 = Ki[0]*dvi0 + Ki[1]*dvi1 + Ki[2]*dvi2;
        float J1 = Ki[3]*dvi0 + Ki[4]*dvi1 + Ki[5]*dvi2;
        float J2 = Ki[6]*dvi0 + Ki[7]*dvi1 + Ki[8]*dvi2;
        float dv0 = J0*inv_mass, dv1 = J1*inv_mass, dv2 = J2*inv_mass;
        float c0 = -Ri2*J1 + Ri1*J2;
        float c1 =  Ri2*J0 - Ri0*J2;
        float c2 = -Ri1*J0 + Ri0*J1;
        float dm0 = Ii[0]*c0 + Ii[1]*c1 + Ii[2]*c2;
        float dm1 = Ii[3]*c0 + Ii[4]*c1 + Ii[5]*c2;
        float dm2 = Ii[6]*c0 + Ii[7]*c1 + Ii[8]*c2;
        bv0 = bv0*ldv + dv0;
        bv1 = (bv1 + C_GYDT)*ldv + dv1;
        bv2 = bv2*ldv + dv2;
        bo0 = bo0*adv + dm0; bo1 = bo1*adv + dm1; bo2 = bo2*adv + dm2;
        btr0 += C_DTF*bv0; btr1 += C_DTF*bv1; btr2 += C_DTF*bv2;
        float wx = bo0*C_HDT, wy = bo1*C_HDT, wz = bo2*C_HDT;
        float dq0 = -wx*bq1 - wy*bq2 - wz*bq3;
        float dq1 =  wx*bq0 + wy*bq3 - wz*bq2;
        float dq2 =  wy*bq0 + wz*bq1 - wx*bq3;
        float dq3 =  wz*bq0 + wx*bq2 - wy*bq1;
        bq0 += dq0; bq1 += dq1; bq2 += dq2; bq3 += dq3;
        float qn2 = sqrtf(bq0*bq0 + bq1*bq1 + bq2*bq2 + bq3*bq3);
        bq0 /= qn2; bq1 /= qn2; bq2 /= qn2; bq3 /= qn2;
        s_state[0] = btr0; s_state[1] = btr1; s_state[2] = btr2;
        s_state[3] = bq0;  s_state[4] = bq1;  s_state[5] = bq2;  s_state[6] = bq3;
        s_state[7] = bv0;  s_state[8] = bv1;  s_state[9] = bv2;
        s_state[10] = bo0; s_state[11] = bo1; s_state[12] = bo2;
        s_state[13] = __uint_as_float((unsigned)(kg + 1) | (1u << 8));
      }
    }
    __syncthreads();
    // ---- broadcast: NREP replicas x 16 words, one coalesced 256-lane store ----
    if (tid < NREP * 16) {
      const int rep = tid >> 4, w = tid & 15;
      rec_store(st + (size_t)buf * NREP * 16 + (size_t)rep * 16 + w,
                rec_pack(s_state[w], want));
    }
    // ---- outputs: off the critical path (after broadcast) ----
    {
      const unsigned meta = __float_as_uint(s_state[13]);
      const int cns = (int)(meta & 0xFFu);
      const int ct  = (int)((meta >> 8) & 1u);
      if (tid == 0) {
        for (int k = 0; k < cns; ++k) {
          float* o = out + (size_t)(t_base + k) * 7;
          if (ct && k == cns - 1) {
            o[0] = s_state[0]; o[1] = s_state[1]; o[2] = s_state[2];
            o[3] = s_state[3]; o[4] = s_state[4]; o[5] = s_state[5]; o[6] = s_state[6];
          } else {
            #pragma unroll
            for (int j = 0; j < 7; ++j) o[j] = s_traj[k+1][j];
          }
        }
      }
      consumed = cns; contact = ct;
    }
  } else {
    // ---- non-leader: poll my replica (<=14 lanes; ~224 pollers per line) ----
    if (tid < 14) {
      const u64* sl = st + (size_t)buf * NREP * 16 + (size_t)(bid & (NREP - 1)) * 16;
      u64 r2; int fl = 0;
      for (;;) {
        r2 = rec_load(sl + tid);
        if ((unsigned)(r2 >> 32) == want) break;
        if ((++fl & 31) == 0) __builtin_amdgcn_s_sleep(1);
      }
      s_state[tid] = __uint_as_float((unsigned)r2);
    }
    __syncthreads();
    const unsigned meta = __float_as_uint(s_state[13]);
    consumed = (int)(meta & 0xFFu);
    contact  = (int)((meta >> 8) & 1u);
  }

  // ==== adopt (uniform): clean -> tid0 keeps its walked S_Kr; contact -> broadcast state
  if (tid == 0 && contact) {
    tr0 = s_state[0]; tr1 = s_state[1]; tr2 = s_state[2];
    q0 = s_state[3]; q1 = s_state[4]; q2 = s_state[5]; q3 = s_state[6];
    v0 = s_state[7]; v1 = s_state[8]; v2 = s_state[9];
    om0 = s_state[10]; om1 = s_state[11]; om2 = s_state[12];
  }
}

__global__ __launch_bounds__(BLOCK)
void sim_kernel(const float* __restrict__ xg,
                const float* __restrict__ mc_p,
                const float* __restrict__ itr_p,
                const float* __restrict__ iq_p,
                const float* __restrict__ iv_p,
                const float* __restrict__ kn_p,
                const float* __restrict__ mu_p,
                const float* __restrict__ ldp_p,
                const float* __restrict__ adp_p,
                float* __restrict__ out,
                u64* __restrict__ ws,
                int N, int T)
{
  const int tid = threadIdx.x;
  const int bid = blockIdx.x;

  extern __shared__ float dyn[];
  float* sXx = dyn;
  float* sXy = dyn + CHUNK;
  float* sXz = dyn + 2 * CHUNK;
  __shared__ float s_red[NWAVES * 16];
  __shared__ float s_planes[KMAX][8];
  __shared__ float s_traj[KMAX + 1][13];
  __shared__ float s_tot[16];
  __shared__ float s_state[16];
  __shared__ int   s_flags;

  const float mc0 = mc_p[0], mc1 = mc_p[1];

  // workspace layout (u64):
  //   part: 2 bufs * 16 words * GRID (SoA: c*GRID + bid)      = 8192
  //   st:   2 bufs * NREP replicas * 16 words                 = 512
  //   bufI: 6*GRID inertia partials                           = 1536
  u64* part = ws;
  u64* st   = ws + 2 * 16 * GRID;
  u64* bufI = ws + 2 * 16 * GRID + 2 * NREP * 16;

  const int vstart = bid * CHUNK;
  int cl = N - vstart; if (cl > CHUNK) cl = CHUNK; if (cl < 0) cl = 0;

  // ---- stage this block's slice of x into LDS (SoA), single global pass ----
  for (int i = tid; i < cl; i += BLOCK) {
    const float* p = xg + (size_t)(vstart + i) * 3;
    sXx[i] = p[0]; sXy[i] = p[1]; sXz[i] = p[2];
  }
  __syncthreads();

  // ---- inertia partial: S[i][j] = sum r_i r_j over this slice ----
  {
    const float m2 = mc_p[2];
    float v6[6] = {0,0,0,0,0,0};
    for (int i = tid; i < cl; i += BLOCK) {
      float r0 = sXx[i] - mc0, r1 = sXy[i] - mc1, r2 = sXz[i] - m2;
      v6[0] += r0*r0; v6[1] += r1*r1; v6[2] += r2*r2;
      v6[3] += r0*r1; v6[4] += r0*r2; v6[5] += r1*r2;
    }
    block_reduce<6>(v6, s_red);
    if (tid == 0) {
      #pragma unroll
      for (int k = 0; k < 6; ++k) rec_store(bufI + k * GRID + bid, rec_pack(v6[k], 0xC0FFEEu));
    }
  }

  // ---- ONLY the leader gathers inertia (contact physics runs only there) ----
  float In[9];
  if (bid == 0) {
    float v6[6] = {0,0,0,0,0,0};
    if (tid < GRID) {
      u64 r[6];
      int f = 0;
      for (;;) {
        #pragma unroll
        for (int k = 0; k < 6; ++k) r[k] = rec_load(bufI + k * GRID + tid);
        bool ok = true;
        #pragma unroll
        for (int k = 0; k < 6; ++k) ok &= ((unsigned)(r[k] >> 32) == 0xC0FFEEu);
        if (ok) break;
        if ((++f & 15) == 0) __builtin_amdgcn_s_sleep(1);
      }
      #pragma unroll
      for (int k = 0; k < 6; ++k) v6[k] = __uint_as_float((unsigned)r[k]);
    }
    block_reduce<6>(v6, s_red);
    float trc = v6[0] + v6[1] + v6[2];
    In[0] = trc - v6[0]; In[4] = trc - v6[1]; In[8] = trc - v6[2];
    In[1] = -v6[3]; In[3] = -v6[3];
    In[2] = -v6[4]; In[6] = -v6[4];
    In[5] = -v6[5]; In[7] = -v6[5];
  }

  // ---- initial state; EVERY block's tid0 holds an identical copy ----
  float tr0 = itr_p[0], tr1 = itr_p[1], tr2 = itr_p[2];
  float q0 = iq_p[0], q1 = iq_p[1], q2 = iq_p[2], q3 = iq_p[3];
  {
    float n0 = sqrtf(q0*q0 + q1*q1 + q2*q2 + q3*q3);
    q0 /= n0; q1 /= n0; q2 /= n0; q3 /= n0;
  }
  float v0 = iv_p[0], v1 = iv_p[1], v2 = iv_p[2];
  float om0 = 0.f, om1 = 0.f, om2 = 0.f;
  const float knv = kn_p[0], muv = mu_p[0], ldv = ldp_p[0], adv = adp_p[0];
  const float inv_mass = 1.0f / (float)N;

  int t_base = 0;
  int rnd = 0;
  int Ksched = KMAX;

  while (t_base < T) {
    const int rem = T - t_base;
    const int Kr = (Ksched < rem) ? Ksched : rem;
    const unsigned want = (unsigned)(rnd + 1);
    const int buf = rnd & 1;
    int consumed, contact, skipped;

    if (Kr <= 1) {
      run_round<1>(1, want, buf, t_base, tr0,tr1,tr2, q0,q1,q2,q3, v0,v1,v2,
                   om0,om1,om2, knv,muv,ldv,adv, inv_mass, mc0,mc1, In,
                   sXx,sXy,sXz, cl, s_red, s_planes, s_traj, s_tot, s_state,
                   &s_flags, part, st, out, consumed, contact, skipped);
    } else if (Kr == 2) {
      run_round<2>(2, want, buf, t_base, tr0,tr1,tr2, q0,q1,q2,q3, v0,v1,v2,
                   om0,om1,om2, knv,muv,ldv,adv, inv_mass, mc0,mc1, In,
                   sXx,sXy,sXz, cl, s_red, s_planes, s_traj, s_tot, s_state,
                   &s_flags, part, st, out, consumed, contact, skipped);
    } else if (Kr <= 4) {
      run_round<4>(Kr, want, buf, t_base, tr0,tr1,tr2, q0,q1,q2,q3, v0,v1,v2,
                   om0,om1,om2, knv,muv,ldv,adv, inv_mass, mc0,mc1, In,
                   sXx,sXy,sXz, cl, s_red, s_planes, s_traj, s_tot, s_state,
                   &s_flags, part, st, out, consumed, contact, skipped);
    } else {
      run_round<8>(Kr, want, buf, t_base, tr0,tr1,tr2, q0,q1,q2,q3, v0,v1,v2,
                   om0,om1,om2, knv,muv,ldv,adv, inv_mass, mc0,mc1, In,
                   sXx,sXy,sXz, cl, s_red, s_planes, s_traj, s_tot, s_state,
                   &s_flags, part, st, out, consumed, contact, skipped);
    }

    t_base += consumed;
    if (!skipped) ++rnd;
    // schedule: full-clean -> grow; truncated/contact -> pow2ceil(consumed)
    // (locks onto period-2 bounce alternation at K=2 instead of resetting to 1)
    Ksched = contact
      ? ((consumed <= 1) ? 1 : (consumed <= 2) ? 2 : (consumed <= 4) ? 4 : KMAX)
      : ((2 * Kr < KMAX) ? 2 * Kr : KMAX);
  }
}

extern "C" void kernel_launch(void* const* d_in, const int* in_sizes, int n_in,
                              void* d_out, int out_size, void* d_ws, size_t ws_size,
                              hipStream_t stream) {
  const float* x   = (const float*)d_in[0];
  const float* mc  = (const float*)d_in[1];
  const float* itr = (const float*)d_in[2];
  const float* iq  = (const float*)d_in[3];
  const float* iv  = (const float*)d_in[4];
  const float* kn  = (const float*)d_in[5];
  const float* mu  = (const float*)d_in[6];
  const float* ldp = (const float*)d_in[7];
  const float* adp = (const float*)d_in[8];
  float* out = (float*)d_out;
  u64* ws  = (u64*)d_ws;
  int N = in_sizes[0] / 3;
  int T = out_size / 7;

  const int dyn_lds = 3 * CHUNK * 4;   // 93756 B < 160 KB/CU
  hipFuncSetAttribute((const void*)sim_kernel,
                      hipFuncAttributeMaxDynamicSharedMemorySize, dyn_lds);

  void* args[] = {(void*)&x, (void*)&mc, (void*)&itr, (void*)&iq, (void*)&iv,
                  (void*)&kn, (void*)&mu, (void*)&ldp, (void*)&adp,
                  (void*)&out, (void*)&ws, (void*)&N, (void*)&T};
  // cooperative launch kept ONLY for the co-residency guarantee (no grid.sync inside)
  hipLaunchCooperativeKernel((void*)sim_kernel, dim3(GRID), dim3(BLOCK),
                             args, dyn_lds, stream);
}